// Round 4
// baseline (269.471 us; speedup 1.0000x reference)
//
#include <hip/hip_runtime.h>
#include <math.h>

#define N_TOK 8192
#define DIM   4096
#define NE    16
#define TOKS  (2*N_TOK)        // 16384
#define NCHUNK (TOKS/64)       // 256
#define D4    (DIM/4)          // 1024 float4 per row
#define NSEG  4
#define SEGF4 (D4/NSEG)        // 256 float4 per segment
#define JITER (SEGF4/64)       // 4

// d_out layout (all float32):
// [0] l_aux | [1..16384] token_pos_after | [16385..32768] token_pos_before
// [32769..32784] expert_token_count | [32785..49168] weight
#define OUT_LAUX 0
#define OUT_TPA  1
#define OUT_TPB  (1+TOKS)
#define OUT_CNT  (1+2*TOKS)
#define OUT_W    (1+2*TOKS+NE)

// K1: partial logits only. 8192 waves = 2048 blocks x 256. Wave = 4 rows x 1
// D-segment (1024 cols). No LDS, no barriers: pure independent load streams.
// Phase-rotated j-loop staggers waves' load bursts to keep misses in flight.
__global__ __launch_bounds__(256) void k1_logits(
    const float4* __restrict__ x4, const float4* __restrict__ wg4,
    float* __restrict__ part)
{
    const int lane  = threadIdx.x & 63;
    const int wave  = threadIdx.x >> 6;
    const int gwave = blockIdx.x * 4 + wave;
    const int seg   = gwave & 3;
    const int row0  = (gwave >> 2) * 4;
    const int ph    = gwave & 3;

    float acc[4][NE];
    #pragma unroll
    for (int r = 0; r < 4; ++r)
        #pragma unroll
        for (int e = 0; e < NE; ++e) acc[r][e] = 0.f;

    #pragma unroll 2
    for (int jj = 0; jj < JITER; ++jj) {
        const int j   = (jj + ph) & (JITER - 1);
        const int col = seg * SEGF4 + j * 64 + lane;
        float4 xv0 = x4[(size_t)(row0 + 0) * D4 + col];
        float4 xv1 = x4[(size_t)(row0 + 1) * D4 + col];
        float4 xv2 = x4[(size_t)(row0 + 2) * D4 + col];
        float4 xv3 = x4[(size_t)(row0 + 3) * D4 + col];
        #pragma unroll
        for (int e = 0; e < NE; ++e) {
            const float4 wv = wg4[e * D4 + col];
            acc[0][e] = fmaf(xv0.x, wv.x, acc[0][e]);
            acc[0][e] = fmaf(xv0.y, wv.y, acc[0][e]);
            acc[0][e] = fmaf(xv0.z, wv.z, acc[0][e]);
            acc[0][e] = fmaf(xv0.w, wv.w, acc[0][e]);
            acc[1][e] = fmaf(xv1.x, wv.x, acc[1][e]);
            acc[1][e] = fmaf(xv1.y, wv.y, acc[1][e]);
            acc[1][e] = fmaf(xv1.z, wv.z, acc[1][e]);
            acc[1][e] = fmaf(xv1.w, wv.w, acc[1][e]);
            acc[2][e] = fmaf(xv2.x, wv.x, acc[2][e]);
            acc[2][e] = fmaf(xv2.y, wv.y, acc[2][e]);
            acc[2][e] = fmaf(xv2.z, wv.z, acc[2][e]);
            acc[2][e] = fmaf(xv2.w, wv.w, acc[2][e]);
            acc[3][e] = fmaf(xv3.x, wv.x, acc[3][e]);
            acc[3][e] = fmaf(xv3.y, wv.y, acc[3][e]);
            acc[3][e] = fmaf(xv3.z, wv.z, acc[3][e]);
            acc[3][e] = fmaf(xv3.w, wv.w, acc[3][e]);
        }
    }

    // per-(r,e) butterfly: all lanes end with the segment total (spill-free)
    #pragma unroll
    for (int r = 0; r < 4; ++r)
        #pragma unroll
        for (int e = 0; e < NE; ++e) {
            float v = acc[r][e];
            v += __shfl_xor(v, 32); v += __shfl_xor(v, 16);
            v += __shfl_xor(v, 8);  v += __shfl_xor(v, 4);
            v += __shfl_xor(v, 2);  v += __shfl_xor(v, 1);
            acc[r][e] = v;
        }

    // lane r (r<4) stores row0+r's 16 partials as 4 float4s
    if (lane < 4) {
        const int r = lane;
        float4* p4 = (float4*)part;
        const size_t base = ((size_t)seg * N_TOK + row0 + r) * 4;
        p4[base + 0] = make_float4(acc[r][0],  acc[r][1],  acc[r][2],  acc[r][3]);
        p4[base + 1] = make_float4(acc[r][4],  acc[r][5],  acc[r][6],  acc[r][7]);
        p4[base + 2] = make_float4(acc[r][8],  acc[r][9],  acc[r][10], acc[r][11]);
        p4[base + 3] = make_float4(acc[r][12], acc[r][13], acc[r][14], acc[r][15]);
    }
}

// K2: combine segment partials (fixed order -> deterministic), top-2, softmax,
// weights, me partials, stable intra-chunk ranks + chunk histograms.
// 64 blocks x 128 threads = 8192 threads, one per row. Wave = one 64-row chunk.
__global__ __launch_bounds__(128) void k2_route(
    const float* __restrict__ part, int* __restrict__ pr,
    int* __restrict__ hist, float* __restrict__ me_part,
    float* __restrict__ out)
{
    const int row   = blockIdx.x * 128 + threadIdx.x;
    const int lane  = threadIdx.x & 63;
    const int gwave = row >> 6;   // chunk index for top-1 half, in [0,128)

    float lg[NE];
    #pragma unroll
    for (int e = 0; e < NE; ++e) lg[e] = 0.f;
    const float4* p4 = (const float4*)part;
    #pragma unroll
    for (int s = 0; s < NSEG; ++s) {
        const size_t base = ((size_t)s * N_TOK + row) * 4;
        #pragma unroll
        for (int q = 0; q < 4; ++q) {
            float4 t = p4[base + q];
            lg[q * 4 + 0] += t.x;
            lg[q * 4 + 1] += t.y;
            lg[q * 4 + 2] += t.z;
            lg[q * 4 + 3] += t.w;
        }
    }

    // top-2; strict > keeps lowest index on ties (matches lax.top_k)
    float m1 = -INFINITY; int i1 = 0;
    #pragma unroll
    for (int e = 0; e < NE; ++e)
        if (lg[e] > m1) { m1 = lg[e]; i1 = e; }
    float m2 = -INFINITY; int i2 = 0;
    #pragma unroll
    for (int e = 0; e < NE; ++e)
        if (e != i1 && lg[e] > m2) { m2 = lg[e]; i2 = e; }

    float ssum = 0.f, ex[NE];
    #pragma unroll
    for (int e = 0; e < NE; ++e) { ex[e] = __expf(lg[e] - m1); ssum += ex[e]; }
    const float inv = 1.f / ssum;

    const float e2v = __expf(m2 - m1);
    const float w1  = 1.f / (1.f + e2v);
    out[OUT_W + row]         = w1;
    out[OUT_W + N_TOK + row] = 1.f - w1;

    // per-wave me partial: butterfly each expert; lane e keeps expert e's sum
    float mymev = 0.f;
    #pragma unroll
    for (int e = 0; e < NE; ++e) {
        float mv = ex[e] * inv;
        mv += __shfl_xor(mv, 32); mv += __shfl_xor(mv, 16);
        mv += __shfl_xor(mv, 8);  mv += __shfl_xor(mv, 4);
        mv += __shfl_xor(mv, 2);  mv += __shfl_xor(mv, 1);
        if (lane == e) mymev = mv;
    }
    if (lane < NE) me_part[gwave * NE + lane] = mymev;

    // stable intra-chunk ranks + chunk histograms via ballot
    const unsigned long long mlt = (1ull << lane) - 1ull;
    int rk1 = 0, rk2 = 0;
    #pragma unroll
    for (int eo = 0; eo < NE; ++eo) {
        unsigned long long mA = __ballot(i1 == eo);
        unsigned long long mB = __ballot(i2 == eo);
        if (i1 == eo) rk1 = (int)__popcll(mA & mlt);
        if (i2 == eo) rk2 = (int)__popcll(mB & mlt);
        if (lane == eo) {
            hist[gwave * NE + eo]                = (int)__popcll(mA);
            hist[(NCHUNK / 2 + gwave) * NE + eo] = (int)__popcll(mB);
        }
    }
    pr[row]         = i1 | (rk1 << 8);
    pr[N_TOK + row] = i2 | (rk2 << 8);
}

// K3: 64 blocks x 256. Every block redundantly scans the 256x16 chunk
// histogram in LDS (16 KB read, ~µs), then places its 256 tokens.
// Block 0 additionally computes l_aux + expert counts.
__global__ __launch_bounds__(256) void k3_place(
    const int* __restrict__ pr, const int* __restrict__ hist,
    const float* __restrict__ me_part, float* __restrict__ out)
{
    __shared__ int   sh[NCHUNK][20];   // padded: 20 KB
    __shared__ int   cnt_sh[NE], ce_sh[NE];
    __shared__ float me_sh[16][17];
    __shared__ float me_tot[NE];

    const int t = threadIdx.x;

    int h[NE];
    {
        const int4* h4 = (const int4*)(hist + t * NE);
        int4 a = h4[0], b = h4[1], c = h4[2], d = h4[3];
        h[0]=a.x; h[1]=a.y; h[2]=a.z; h[3]=a.w;
        h[4]=b.x; h[5]=b.y; h[6]=b.z; h[7]=b.w;
        h[8]=c.x; h[9]=c.y; h[10]=c.z; h[11]=c.w;
        h[12]=d.x; h[13]=d.y; h[14]=d.z; h[15]=d.w;
    }
    #pragma unroll
    for (int e = 0; e < NE; ++e) sh[t][e] = h[e];
    __syncthreads();

    // Hillis-Steele inclusive scan over 256 chunks, all 16 experts at once
    for (int off = 1; off < NCHUNK; off <<= 1) {
        int tmp[NE];
        #pragma unroll
        for (int e = 0; e < NE; ++e) tmp[e] = (t >= off) ? sh[t - off][e] : 0;
        __syncthreads();
        #pragma unroll
        for (int e = 0; e < NE; ++e) sh[t][e] += tmp[e];
        __syncthreads();
    }

    if (t == NCHUNK - 1) {
        #pragma unroll
        for (int e = 0; e < NE; ++e) cnt_sh[e] = sh[t][e];
    }
    if (t == NCHUNK / 2 - 1) {
        #pragma unroll
        for (int e = 0; e < NE; ++e) ce_sh[e] = sh[t][e];  // top-1 totals
    }

    // convert to exclusive in place
    int ex[NE];
    #pragma unroll
    for (int e = 0; e < NE; ++e) ex[e] = sh[t][e] - h[e];
    __syncthreads();
    #pragma unroll
    for (int e = 0; e < NE; ++e) sh[t][e] = ex[e];
    __syncthreads();

    int offs[NE];
    {
        int run = 0;
        #pragma unroll
        for (int e = 0; e < NE; ++e) { offs[e] = run; run += cnt_sh[e]; }
    }

    // place this block's 256 tokens
    {
        const int tk = blockIdx.x * 256 + t;
        const int v  = pr[tk];
        const int e  = v & 255;
        const int rk = v >> 8;
        const int c  = tk >> 6;   // global chunk, sh holds all 256
        const int pos = sh[c][e] + offs[e] + rk;
        out[OUT_TPA + tk]  = (float)pos;
        out[OUT_TPB + pos] = (float)tk;
    }

    // block 0: l_aux + counts
    if (blockIdx.x == 0) {
        {
            const int e = t & 15, g = t >> 4;   // g in [0,16)
            float s = 0.f;
            #pragma unroll
            for (int k = 0; k < 8; ++k) s += me_part[(g + 16 * k) * NE + e];
            me_sh[g][e] = s;
        }
        __syncthreads();
        if (t < NE) {
            float me = 0.f;
            #pragma unroll
            for (int g = 0; g < 16; ++g) me += me_sh[g][t];
            me_tot[t] = me;
            out[OUT_CNT + t] = (float)cnt_sh[t];
        }
        __syncthreads();
        if (t == 0) {
            float la = 0.f;
            #pragma unroll
            for (int e = 0; e < NE; ++e)
                la += (me_tot[e] * (1.0f / N_TOK)) * ((float)ce_sh[e] * (1.0f / N_TOK));
            out[OUT_LAUX] = la * (float)NE;
        }
    }
}

extern "C" void kernel_launch(void* const* d_in, const int* in_sizes, int n_in,
                              void* d_out, int out_size, void* d_ws, size_t ws_size,
                              hipStream_t stream) {
    const float* x  = (const float*)d_in[0];   // [8192,4096] fp32
    const float* wg = (const float*)d_in[1];   // [16,4096] fp32
    float* out = (float*)d_out;

    char* w = (char*)d_ws;
    float* part    = (float*)w;  w += (size_t)NSEG * N_TOK * NE * sizeof(float); // 2 MB
    int*   pr      = (int*)w;    w += TOKS * sizeof(int);         // 64 KB
    int*   hist    = (int*)w;    w += NCHUNK * NE * sizeof(int);  // 16 KB
    float* me_part = (float*)w;                                   // 8 KB

    k1_logits<<<(N_TOK / 4) * NSEG / 4, 256, 0, stream>>>(
        (const float4*)x, (const float4*)wg, part);
    k2_route<<<N_TOK / 128, 128, 0, stream>>>(part, pr, hist, me_part, out);
    k3_place<<<TOKS / 256, 256, 0, stream>>>(pr, hist, me_part, out);
}

// Round 5
// 215.497 us; speedup vs baseline: 1.2505x; 1.2505x over previous
//
#include <hip/hip_runtime.h>
#include <math.h>

#define N_TOK 8192
#define DIM   4096
#define NE    16
#define TOKS  (2*N_TOK)        // 16384
#define NCHUNK (TOKS/64)       // 256
#define D4    (DIM/4)          // 1024 float4 per row
#define NSEGG 8                // D seg-groups (512 cols each); part combine depth
#define SLICEF4 128            // float4 per block slice (512 cols)

// d_out layout (all float32):
// [0] l_aux | [1..16384] token_pos_after | [16385..32768] token_pos_before
// [32769..32784] expert_token_count | [32785..49168] weight
#define OUT_LAUX 0
#define OUT_TPA  1
#define OUT_TPB  (1+TOKS)
#define OUT_CNT  (1+2*TOKS)
#define OUT_W    (1+2*TOKS+NE)

// K1: lane-per-row partial logits. 1024 blocks x 256 threads.
// Block = 64 rows x one 512-col slice (g = blockIdx&7). Wave w covers the
// 128-col quarter w of the slice, all 64 rows (lane = row).
// - x: each load instr touches 64 distinct 128B lines (max miss-level
//   parallelism); each lane consumes its whole line immediately (8 xq loads).
// - Wg: staged once per block into LDS (32 KB); in-loop reads are
//   wave-uniform ds_read broadcasts -> zero vmem traffic.
// - acc is per-lane (16 regs), no cross-lane reduce, no spill pressure.
__global__ __launch_bounds__(256) void k1_rowlane(
    const float4* __restrict__ x4, const float4* __restrict__ wg4,
    float* __restrict__ part)
{
    __shared__ float4 wgl[NE][SLICEF4];   // 32 KB  [e][slice f4]
    __shared__ float  pl[4][64][NE];      // 16 KB  [wave][row][e]

    const int tid  = threadIdx.x;
    const int lane = tid & 63;
    const int w    = tid >> 6;            // 0..3
    const int g    = blockIdx.x & 7;      // slice group (512 cols)
    const int rg   = blockIdx.x >> 3;     // row group (64 rows)

    // ---- stage Wg slice: 2048 float4, 8 per thread, coalesced ----
    #pragma unroll
    for (int i = 0; i < 8; ++i) {
        const int idx = i * 256 + tid;
        const int e = idx >> 7, c = idx & 127;
        wgl[e][c] = wg4[(size_t)e * D4 + g * SLICEF4 + c];
    }
    __syncthreads();

    const int row = rg * 64 + lane;
    const float4* xrow = x4 + (size_t)row * D4 + g * SLICEF4 + w * 32;

    float acc[NE];
    #pragma unroll
    for (int e = 0; e < NE; ++e) acc[e] = 0.f;

    #pragma unroll
    for (int si = 0; si < 4; ++si) {
        float4 xq[8];
        #pragma unroll
        for (int k = 0; k < 8; ++k) xq[k] = xrow[si * 8 + k];
        #pragma unroll
        for (int e = 0; e < NE; ++e) {
            float a = acc[e];
            #pragma unroll
            for (int k = 0; k < 8; ++k) {
                const float4 wv = wgl[e][w * 32 + si * 8 + k];   // uniform -> broadcast
                a = fmaf(xq[k].x, wv.x, a);
                a = fmaf(xq[k].y, wv.y, a);
                a = fmaf(xq[k].z, wv.z, a);
                a = fmaf(xq[k].w, wv.w, a);
            }
            acc[e] = a;
        }
    }

    // ---- combine the 4 waves' quarter-slices through LDS ----
    #pragma unroll
    for (int e = 0; e < NE; ++e) pl[w][lane][e] = acc[e];
    __syncthreads();

    // 1024 sums; 4 per thread; output contiguous per block (coalesced)
    #pragma unroll
    for (int j = 0; j < 4; ++j) {
        const int flat = j * 256 + tid;       // = r*16 + e
        const int r = flat >> 4, e = flat & 15;
        const float s = pl[0][r][e] + pl[1][r][e] + pl[2][r][e] + pl[3][r][e];
        part[(size_t)g * (N_TOK * NE) + (size_t)rg * 1024 + flat] = s;
    }
}

// K2: combine 8 slice partials (fixed order -> deterministic), top-2, softmax,
// weights, me partials, stable intra-chunk ranks + chunk histograms.
// 64 blocks x 128 threads, one thread per row. Wave = one 64-row chunk.
__global__ __launch_bounds__(128) void k2_route(
    const float* __restrict__ part, int* __restrict__ pr,
    int* __restrict__ hist, float* __restrict__ me_part,
    float* __restrict__ out)
{
    const int row   = blockIdx.x * 128 + threadIdx.x;
    const int lane  = threadIdx.x & 63;
    const int gwave = row >> 6;   // chunk index for top-1 half, in [0,128)

    float lg[NE];
    #pragma unroll
    for (int e = 0; e < NE; ++e) lg[e] = 0.f;
    const float4* p4 = (const float4*)part;
    #pragma unroll
    for (int s = 0; s < NSEGG; ++s) {
        const size_t base = ((size_t)s * N_TOK + row) * 4;
        #pragma unroll
        for (int q = 0; q < 4; ++q) {
            float4 t = p4[base + q];
            lg[q * 4 + 0] += t.x;
            lg[q * 4 + 1] += t.y;
            lg[q * 4 + 2] += t.z;
            lg[q * 4 + 3] += t.w;
        }
    }

    // top-2; strict > keeps lowest index on ties (matches lax.top_k)
    float m1 = -INFINITY; int i1 = 0;
    #pragma unroll
    for (int e = 0; e < NE; ++e)
        if (lg[e] > m1) { m1 = lg[e]; i1 = e; }
    float m2 = -INFINITY; int i2 = 0;
    #pragma unroll
    for (int e = 0; e < NE; ++e)
        if (e != i1 && lg[e] > m2) { m2 = lg[e]; i2 = e; }

    float ssum = 0.f, ex[NE];
    #pragma unroll
    for (int e = 0; e < NE; ++e) { ex[e] = __expf(lg[e] - m1); ssum += ex[e]; }
    const float inv = 1.f / ssum;

    const float e2v = __expf(m2 - m1);
    const float w1  = 1.f / (1.f + e2v);
    out[OUT_W + row]         = w1;
    out[OUT_W + N_TOK + row] = 1.f - w1;

    // per-wave me partial: butterfly each expert; lane e keeps expert e's sum
    float mymev = 0.f;
    #pragma unroll
    for (int e = 0; e < NE; ++e) {
        float mv = ex[e] * inv;
        mv += __shfl_xor(mv, 32); mv += __shfl_xor(mv, 16);
        mv += __shfl_xor(mv, 8);  mv += __shfl_xor(mv, 4);
        mv += __shfl_xor(mv, 2);  mv += __shfl_xor(mv, 1);
        if (lane == e) mymev = mv;
    }
    if (lane < NE) me_part[gwave * NE + lane] = mymev;

    // stable intra-chunk ranks + chunk histograms via ballot
    const unsigned long long mlt = (1ull << lane) - 1ull;
    int rk1 = 0, rk2 = 0;
    #pragma unroll
    for (int eo = 0; eo < NE; ++eo) {
        unsigned long long mA = __ballot(i1 == eo);
        unsigned long long mB = __ballot(i2 == eo);
        if (i1 == eo) rk1 = (int)__popcll(mA & mlt);
        if (i2 == eo) rk2 = (int)__popcll(mB & mlt);
        if (lane == eo) {
            hist[gwave * NE + eo]                = (int)__popcll(mA);
            hist[(NCHUNK / 2 + gwave) * NE + eo] = (int)__popcll(mB);
        }
    }
    pr[row]         = i1 | (rk1 << 8);
    pr[N_TOK + row] = i2 | (rk2 << 8);
}

// K3: 64 blocks x 256. Every block redundantly scans the 256x16 chunk
// histogram in LDS, then places its 256 tokens. Block 0 adds l_aux + counts.
__global__ __launch_bounds__(256) void k3_place(
    const int* __restrict__ pr, const int* __restrict__ hist,
    const float* __restrict__ me_part, float* __restrict__ out)
{
    __shared__ int   sh[NCHUNK][20];   // padded
    __shared__ int   cnt_sh[NE], ce_sh[NE];
    __shared__ float me_sh[16][17];
    __shared__ float me_tot[NE];

    const int t = threadIdx.x;

    int h[NE];
    {
        const int4* h4 = (const int4*)(hist + t * NE);
        int4 a = h4[0], b = h4[1], c = h4[2], d = h4[3];
        h[0]=a.x; h[1]=a.y; h[2]=a.z; h[3]=a.w;
        h[4]=b.x; h[5]=b.y; h[6]=b.z; h[7]=b.w;
        h[8]=c.x; h[9]=c.y; h[10]=c.z; h[11]=c.w;
        h[12]=d.x; h[13]=d.y; h[14]=d.z; h[15]=d.w;
    }
    #pragma unroll
    for (int e = 0; e < NE; ++e) sh[t][e] = h[e];
    __syncthreads();

    for (int off = 1; off < NCHUNK; off <<= 1) {
        int tmp[NE];
        #pragma unroll
        for (int e = 0; e < NE; ++e) tmp[e] = (t >= off) ? sh[t - off][e] : 0;
        __syncthreads();
        #pragma unroll
        for (int e = 0; e < NE; ++e) sh[t][e] += tmp[e];
        __syncthreads();
    }

    if (t == NCHUNK - 1) {
        #pragma unroll
        for (int e = 0; e < NE; ++e) cnt_sh[e] = sh[t][e];
    }
    if (t == NCHUNK / 2 - 1) {
        #pragma unroll
        for (int e = 0; e < NE; ++e) ce_sh[e] = sh[t][e];  // top-1 totals
    }

    int ex[NE];
    #pragma unroll
    for (int e = 0; e < NE; ++e) ex[e] = sh[t][e] - h[e];
    __syncthreads();
    #pragma unroll
    for (int e = 0; e < NE; ++e) sh[t][e] = ex[e];
    __syncthreads();

    int offs[NE];
    {
        int run = 0;
        #pragma unroll
        for (int e = 0; e < NE; ++e) { offs[e] = run; run += cnt_sh[e]; }
    }

    {
        const int tk = blockIdx.x * 256 + t;
        const int v  = pr[tk];
        const int e  = v & 255;
        const int rk = v >> 8;
        const int c  = tk >> 6;
        const int pos = sh[c][e] + offs[e] + rk;
        out[OUT_TPA + tk]  = (float)pos;
        out[OUT_TPB + pos] = (float)tk;
    }

    if (blockIdx.x == 0) {
        {
            const int e = t & 15, gg = t >> 4;   // gg in [0,16)
            float s = 0.f;
            #pragma unroll
            for (int k = 0; k < 8; ++k) s += me_part[(gg + 16 * k) * NE + e];
            me_sh[gg][e] = s;
        }
        __syncthreads();
        if (t < NE) {
            float me = 0.f;
            #pragma unroll
            for (int gg = 0; gg < 16; ++gg) me += me_sh[gg][t];
            me_tot[t] = me;
            out[OUT_CNT + t] = (float)cnt_sh[t];
        }
        __syncthreads();
        if (t == 0) {
            float la = 0.f;
            #pragma unroll
            for (int e = 0; e < NE; ++e)
                la += (me_tot[e] * (1.0f / N_TOK)) * ((float)ce_sh[e] * (1.0f / N_TOK));
            out[OUT_LAUX] = la * (float)NE;
        }
    }
}

extern "C" void kernel_launch(void* const* d_in, const int* in_sizes, int n_in,
                              void* d_out, int out_size, void* d_ws, size_t ws_size,
                              hipStream_t stream) {
    const float* x  = (const float*)d_in[0];   // [8192,4096] fp32
    const float* wg = (const float*)d_in[1];   // [16,4096] fp32
    float* out = (float*)d_out;

    char* w = (char*)d_ws;
    float* part    = (float*)w;  w += (size_t)NSEGG * N_TOK * NE * sizeof(float); // 4 MB
    int*   pr      = (int*)w;    w += TOKS * sizeof(int);         // 64 KB
    int*   hist    = (int*)w;    w += NCHUNK * NE * sizeof(int);  // 16 KB
    float* me_part = (float*)w;                                   // 8 KB

    k1_rowlane<<<(N_TOK / 64) * NSEGG, 256, 0, stream>>>(
        (const float4*)x, (const float4*)wg, part);
    k2_route<<<N_TOK / 128, 128, 0, stream>>>(part, pr, hist, me_part, out);
    k3_place<<<TOKS / 256, 256, 0, stream>>>(pr, hist, me_part, out);
}